// Round 2
// baseline (1158.469 us; speedup 1.0000x reference)
//
#include <hip/hip_runtime.h>
#include <hip/hip_bf16.h>
#include <stdint.h>

// Problem constants (from reference)
#define NN 50000
#define NE 800000
#define DV 133
#define DE 14
#define DH 300

typedef unsigned short ushort_t;
typedef __attribute__((ext_vector_type(8))) short short8;
typedef __attribute__((ext_vector_type(4))) float f32x4;

__device__ __forceinline__ float bf2f(ushort_t u) {
  union { unsigned int i; float f; } v; v.i = ((unsigned int)u) << 16; return v.f;
}
__device__ __forceinline__ ushort_t f2bf(float f) {
  union { unsigned int i; float f; } v; v.f = f;
  unsigned int u = v.i;
  return (ushort_t)((u + 0x7fffu + ((u >> 16) & 1u)) >> 16);
}
__device__ __forceinline__ float u_lo(unsigned int u) {
  union { unsigned int i; float f; } v; v.i = u << 16; return v.f;
}
__device__ __forceinline__ float u_hi(unsigned int u) {
  union { unsigned int i; float f; } v; v.i = u & 0xffff0000u; return v.f;
}

// ---------------- edge_index dtype detection (int64 vs int32) ----------------
// If stored as int64 (little-endian, values in [0,50000)), every odd int32 slot
// is a zero high-word. In int32 mode those slots are random edge ids; the
// probability 1024 of them are all zero is ~(2e-5)^1024.
__global__ void detect_kernel(const int* __restrict__ ei32, int* __restrict__ flag) {
  __shared__ int s_or;
  if (threadIdx.x == 0) s_or = 0;
  __syncthreads();
  int v = ei32[2 * threadIdx.x + 1] | ei32[2 * (threadIdx.x + 256) + 1] |
          ei32[2 * (threadIdx.x + 512) + 1] | ei32[2 * (threadIdx.x + 768) + 1];
  if (v) atomicOr(&s_or, 1);
  __syncthreads();
  if (threadIdx.x == 0) *flag = (s_or == 0) ? 1 : 0;
}

__global__ void decode_kernel(const void* __restrict__ ei_raw, const int* __restrict__ flag,
                              int* __restrict__ src32, int* __restrict__ dst32) {
  int e = blockIdx.x * blockDim.x + threadIdx.x;
  if (e >= NE) return;
  if (*flag) {
    const long long* p = (const long long*)ei_raw;
    src32[e] = (int)p[e];
    dst32[e] = (int)p[NE + e];
  } else {
    const int* p = (const int*)ei_raw;
    src32[e] = p[e];
    dst32[e] = p[NE + e];
  }
}

// ---------------- conversion: f32 submatrix -> zero-padded bf16 ----------------
__global__ void convert_pad_kernel(const float* __restrict__ src, int src_ld, int col_off,
                                   int rows, int cols, ushort_t* __restrict__ dst, int dst_ld,
                                   long total) {
  long gid = (long)blockIdx.x * blockDim.x + threadIdx.x;
  if (gid >= total) return;
  int r = (int)(gid / dst_ld), c = (int)(gid % dst_ld);
  float v = (r < rows && c < cols) ? src[(long)r * src_ld + col_off + c] : 0.f;
  dst[gid] = f2bf(v);
}

// ---------------- per-dst edge-feature sums + degree counts ----------------
__global__ void esum_count_kernel(const int* __restrict__ dst32, const float* __restrict__ Ef,
                                  float* __restrict__ Esum, int* __restrict__ counts) {
  int gid = blockIdx.x * blockDim.x + threadIdx.x;
  int e = gid >> 4, k = gid & 15;
  if (e >= NE) return;
  int dst = dst32[e];
  if (k < DE) atomicAdd(&Esum[dst * DE + k], Ef[(long)e * DE + k]);
  if (k == 15) atomicAdd(&counts[dst], 1);
}

// ---------------- single-block exclusive scan (50001 entries) ----------------
__global__ void scan_kernel(const int* __restrict__ counts, int* __restrict__ rp,
                            int* __restrict__ cursor, int n) {
  __shared__ int buf[1024];
  __shared__ int carry_s;
  int t = threadIdx.x;
  if (t == 0) carry_s = 0;
  __syncthreads();
  for (int base = 0; base < n; base += 1024) {
    int i = base + t;
    int v = (i < n) ? counts[i] : 0;
    buf[t] = v;
    __syncthreads();
    for (int offd = 1; offd < 1024; offd <<= 1) {
      int add = (t >= offd) ? buf[t - offd] : 0;
      __syncthreads();
      buf[t] += add;
      __syncthreads();
    }
    int carry = carry_s;
    int excl = buf[t] - v + carry;
    int total = buf[1023];
    if (i < n) { rp[i] = excl; cursor[i] = excl; }
    __syncthreads();
    if (t == 0) carry_s = carry + total;
    __syncthreads();
  }
  if (t == 0) rp[n] = carry_s;
}

// ---------------- CSR fill: bucket src ids by dst ----------------
__global__ void fill_kernel(const int* __restrict__ src32, const int* __restrict__ dst32,
                            int* __restrict__ cursor, int* __restrict__ ssrc) {
  int e = blockIdx.x * blockDim.x + threadIdx.x;
  if (e >= NE) return;
  int dst = dst32[e];
  int pos = atomicAdd(&cursor[dst], 1);
  ssrc[pos] = src32[e];
}

// ---------------- constant term C = Esum @ W_hE^T + deg * b_h ----------------
__global__ void cterm_kernel(const float* __restrict__ Esum, const int* __restrict__ rp,
                             const float* __restrict__ W_h, const float* __restrict__ b_h,
                             ushort_t* __restrict__ Cb) {
  int n = blockIdx.y;
  int j = blockIdx.x * blockDim.x + threadIdx.x;
  if (j >= DH) return;
  float deg = (float)(rp[n + 1] - rp[n]);
  float acc = deg * b_h[j];
#pragma unroll
  for (int k = 0; k < DE; k++) acc += Esum[n * DE + k] * W_h[j * (DH + DE) + DH + k];
  Cb[(long)n * DH + j] = f2bf(acc);
}

// ---------------- segment-sum via CSR gather: A[n] = sum_{e:dst=n} H[src_e] ----------------
// one wave per node; row stride 384 bf16 = 768B = 64 lanes x 12B, fully coalesced
__global__ void gather_scatter_kernel(const ushort_t* __restrict__ H, const int* __restrict__ rp,
                                      const int* __restrict__ ssrc, ushort_t* __restrict__ A) {
  int wave = blockIdx.x * (blockDim.x >> 6) + (threadIdx.x >> 6);
  int lane = threadIdx.x & 63;
  if (wave >= NN) return;
  int start = rp[wave], end = rp[wave + 1];
  float a0 = 0, a1 = 0, a2 = 0, a3 = 0, a4 = 0, a5 = 0;
  const unsigned int* base = (const unsigned int*)H;
  int off = lane * 3;  // uint offset in a 192-uint row
  int i = start;
  for (; i + 1 < end; i += 2) {
    int s0 = ssrc[i], s1 = ssrc[i + 1];
    const unsigned int* p0 = base + (long)s0 * 192 + off;
    const unsigned int* p1 = base + (long)s1 * 192 + off;
    unsigned int x0 = p0[0], x1 = p0[1], x2 = p0[2];
    unsigned int y0 = p1[0], y1 = p1[1], y2 = p1[2];
    a0 += u_lo(x0); a1 += u_hi(x0); a2 += u_lo(x1); a3 += u_hi(x1); a4 += u_lo(x2); a5 += u_hi(x2);
    a0 += u_lo(y0); a1 += u_hi(y0); a2 += u_lo(y1); a3 += u_hi(y1); a4 += u_lo(y2); a5 += u_hi(y2);
  }
  if (i < end) {
    int s0 = ssrc[i];
    const unsigned int* p0 = base + (long)s0 * 192 + off;
    unsigned int x0 = p0[0], x1 = p0[1], x2 = p0[2];
    a0 += u_lo(x0); a1 += u_hi(x0); a2 += u_lo(x1); a3 += u_hi(x1); a4 += u_lo(x2); a5 += u_hi(x2);
  }
  unsigned int* q = (unsigned int*)A + (long)wave * 192 + off;
  q[0] = (unsigned int)f2bf(a0) | ((unsigned int)f2bf(a1) << 16);
  q[1] = (unsigned int)f2bf(a2) | ((unsigned int)f2bf(a3) << 16);
  q[2] = (unsigned int)f2bf(a4) | ((unsigned int)f2bf(a5) << 16);
}

// ---------------- bf16 MFMA GEMM: out = relu(A1@W1^T [+ A2@W2^T] + bias + add1 + add2) ----
// block: 256 thr = 4 waves; tile = 64 rows x 304 cols (19 col-frags of 16).
// Wave w owns col-frags cf = w + 4*i (i<5, cf<19) and ALL 4 row-frags -> acc[4][5].
// Union over 4 waves covers the full 64x304 tile (76 = 4x19 MFMA D-tiles).
// LDS stride 40 shorts (80B) -> conflict-free ds_read_b128.
#define SLDA 40
__global__ __launch_bounds__(256) void gemm_kernel(
    const ushort_t* __restrict__ A1, int lda1, int nks1,
    const ushort_t* __restrict__ W1, int ldw1,
    const ushort_t* __restrict__ A2, int lda2, int nks2,
    const ushort_t* __restrict__ W2, int ldw2,
    const float* __restrict__ bias,
    const ushort_t* __restrict__ add1, const ushort_t* __restrict__ add2,
    ushort_t* __restrict__ outB, int ldoutB,
    ushort_t* __restrict__ outB2,
    float* __restrict__ outF) {
  __shared__ ushort_t sA[64 * SLDA];
  __shared__ ushort_t sW[304 * SLDA];
  int tid = threadIdx.x;
  int w = tid >> 6, lane = tid & 63;
  int rowbase = blockIdx.x * 64;
  f32x4 acc[4][5];
#pragma unroll
  for (int rf = 0; rf < 4; rf++)
#pragma unroll
    for (int i = 0; i < 5; i++) acc[rf][i] = (f32x4){0.f, 0.f, 0.f, 0.f};

  int strow = tid >> 2, stslot = tid & 3;
  int mrow = lane & 15;
  int koff = (lane >> 4) * 8;

  for (int pass = 0; pass < 2; pass++) {
    const ushort_t* Ap = (pass == 0) ? A1 : A2;
    const ushort_t* Wp = (pass == 0) ? W1 : W2;
    int lda = (pass == 0) ? lda1 : lda2;
    int ldw = (pass == 0) ? ldw1 : ldw2;
    int nks = (pass == 0) ? nks1 : nks2;
    for (int ks = 0; ks < nks; ks++) {
      {
        int gr = rowbase + strow;
        uint4 val = {0u, 0u, 0u, 0u};
        if (gr < NN) val = *(const uint4*)(Ap + (long)gr * lda + ks * 32 + stslot * 8);
        *(uint4*)(&sA[strow * SLDA + stslot * 8]) = val;
      }
#pragma unroll
      for (int i = 0; i < 5; i++) {
        int idx = tid + 256 * i;
        if (idx < 1216) {
          int r = idx >> 2, sl = idx & 3;
          uint4 val = *(const uint4*)(Wp + (long)r * ldw + ks * 32 + sl * 8);
          *(uint4*)(&sW[r * SLDA + sl * 8]) = val;
        }
      }
      __syncthreads();
      short8 af[4];
#pragma unroll
      for (int rf = 0; rf < 4; rf++)
        af[rf] = *(const short8*)(&sA[(rf * 16 + mrow) * SLDA + koff]);
#pragma unroll
      for (int i = 0; i < 5; i++) {
        int cf = w + 4 * i;
        if (cf < 19) {
          short8 bfr = *(const short8*)(&sW[(cf * 16 + mrow) * SLDA + koff]);
#pragma unroll
          for (int rf = 0; rf < 4; rf++)
            acc[rf][i] = __builtin_amdgcn_mfma_f32_16x16x32_bf16(af[rf], bfr, acc[rf][i], 0, 0, 0);
        }
      }
      __syncthreads();
    }
  }
  // epilogue: D layout col = lane&15, row = (lane>>4)*4 + reg
  int rloc = (lane >> 4) * 4;
  int cloc = lane & 15;
#pragma unroll
  for (int rf = 0; rf < 4; rf++) {
    for (int i = 0; i < 5; i++) {
      int cf = w + 4 * i;
      if (cf >= 19) continue;
      int gc = cf * 16 + cloc;
      if (gc >= DH) continue;
#pragma unroll
      for (int r = 0; r < 4; r++) {
        int gr = rowbase + rf * 16 + rloc + r;
        if (gr >= NN) continue;
        float v = acc[rf][i][r];
        if (bias) v += bias[gc];
        if (add1) v += bf2f(add1[(long)gr * DH + gc]);
        if (add2) v += bf2f(add2[(long)gr * DH + gc]);
        v = fmaxf(v, 0.f);
        if (outB) outB[(long)gr * ldoutB + gc] = f2bf(v);
        if (outB2) outB2[(long)gr * DH + gc] = f2bf(v);
        if (outF) outF[(long)gr * DH + gc] = v;
      }
    }
  }
}

extern "C" void kernel_launch(void* const* d_in, const int* in_sizes, int n_in,
                              void* d_out, int out_size, void* d_ws, size_t ws_size,
                              hipStream_t stream) {
  const float* V   = (const float*)d_in[0];
  const float* E   = (const float*)d_in[1];
  const void*  ei  = d_in[2];
  const float* W_i = (const float*)d_in[3];
  const float* b_i = (const float*)d_in[4];
  const float* W_h = (const float*)d_in[5];
  const float* b_h = (const float*)d_in[6];
  const float* W_o = (const float*)d_in[7];
  const float* b_o = (const float*)d_in[8];
  float* out = (float*)d_out;

  char* ws = (char*)d_ws;
  size_t off = 0;
  auto alloc = [&](size_t bytes) {
    void* p = ws + off;
    off = (off + bytes + 255) & ~(size_t)255;
    return p;
  };
  ushort_t* Vbf  = (ushort_t*)alloc((size_t)NN * 160 * 2);
  ushort_t* Hb   = (ushort_t*)alloc((size_t)NN * 384 * 2);
  ushort_t* H0b  = (ushort_t*)alloc((size_t)NN * 300 * 2);
  ushort_t* Ab   = (ushort_t*)alloc((size_t)NN * 384 * 2);
  ushort_t* Cb   = (ushort_t*)alloc((size_t)NN * 300 * 2);
  ushort_t* Wib  = (ushort_t*)alloc((size_t)304 * 160 * 2);
  ushort_t* WhHb = (ushort_t*)alloc((size_t)304 * 320 * 2);
  ushort_t* WoVb = (ushort_t*)alloc((size_t)304 * 160 * 2);
  ushort_t* WoHb = (ushort_t*)alloc((size_t)304 * 320 * 2);
  float*  Esum   = (float*)alloc((size_t)NN * DE * 4);
  int* counts    = (int*)alloc((size_t)NN * 4);
  int* rp        = (int*)alloc((size_t)(NN + 4) * 4);
  int* cursor    = (int*)alloc((size_t)NN * 4);
  int* ssrc      = (int*)alloc((size_t)NE * 4);
  int* src32     = (int*)alloc((size_t)NE * 4);
  int* dst32     = (int*)alloc((size_t)NE * 4);
  int* flag      = (int*)alloc(256);

  // zero-init: K-pad columns of Hb must be 0 for MFMA; Esum/counts accumulate
  hipMemsetAsync(Hb, 0, (size_t)NN * 384 * 2, stream);
  hipMemsetAsync(Esum, 0, (size_t)NN * DE * 4, stream);
  hipMemsetAsync(counts, 0, (size_t)NN * 4, stream);

  // normalize edge_index to int32 src/dst regardless of on-device dtype
  detect_kernel<<<1, 256, 0, stream>>>((const int*)ei, flag);
  decode_kernel<<<(NE + 255) / 256, 256, 0, stream>>>(ei, flag, src32, dst32);

  auto conv = [&](const float* src, int sld, int coff, int rows, int cols,
                  ushort_t* dst, int dld, int drows) {
    long total = (long)drows * dld;
    convert_pad_kernel<<<(int)((total + 255) / 256), 256, 0, stream>>>(
        src, sld, coff, rows, cols, dst, dld, total);
  };
  conv(V, DV, 0, NN, DV, Vbf, 160, NN);
  conv(W_i, DV, 0, DH, DV, Wib, 160, 304);
  conv(W_h, DH + DE, 0, DH, DH, WhHb, 320, 304);
  conv(W_o, DV + DH, 0, DH, DV, WoVb, 160, 304);
  conv(W_o, DV + DH, DV, DH, DH, WoHb, 320, 304);

  esum_count_kernel<<<NE * 16 / 256, 256, 0, stream>>>(dst32, E, Esum, counts);

  // H0 = relu(V @ W_i^T + b_i); write both the padded iteration state Hb and H0b
  gemm_kernel<<<(NN + 63) / 64, 256, 0, stream>>>(
      Vbf, 160, 5, Wib, 160, nullptr, 0, 0, nullptr, 0,
      b_i, nullptr, nullptr, Hb, 384, H0b, nullptr);

  scan_kernel<<<1, 1024, 0, stream>>>(counts, rp, cursor, NN);
  fill_kernel<<<(NE + 255) / 256, 256, 0, stream>>>(src32, dst32, cursor, ssrc);
  cterm_kernel<<<dim3(2, NN), 256, 0, stream>>>(Esum, rp, W_h, b_h, Cb);

  for (int it = 0; it < 2; it++) {
    gather_scatter_kernel<<<NN / 4, 256, 0, stream>>>(Hb, rp, ssrc, Ab);
    // H = relu(H0 + A @ W_hH^T + C)   (b_h is inside C as deg*b_h)
    gemm_kernel<<<(NN + 63) / 64, 256, 0, stream>>>(
        Ab, 384, 10, WhHb, 320, nullptr, 0, 0, nullptr, 0,
        nullptr, H0b, Cb, Hb, 384, nullptr, nullptr);
  }
  gather_scatter_kernel<<<NN / 4, 256, 0, stream>>>(Hb, rp, ssrc, Ab);
  // H_v = relu(V @ W_oV^T + M_v @ W_oH^T + b_o) -> f32 d_out
  gemm_kernel<<<(NN + 63) / 64, 256, 0, stream>>>(
      Vbf, 160, 5, WoVb, 160, Ab, 384, 10, WoHb, 320,
      b_o, nullptr, nullptr, nullptr, 0, nullptr, out);
}